// Round 10
// baseline (244.825 us; speedup 1.0000x reference)
//
#include <hip/hip_runtime.h>

// ACCriticNSMsg — v5: SINGLE kernel, no d_ws (v4's two-kernel/d_ws design
// corrupted timed graph replays: first call passed, replays diverged 0.5 —
// suspected ws_size overflow or inter-kernel d_ws visibility; both removed).
//
// bs=64,T=256,n=8,msg=16,obs=128,hid=64,in_dim=240. out (bs,T,n,1) f32.
//
// Structure: grid (64, 8) x 256 thr. Block (g, a) processes 4 consecutive
// 64-row m-tiles of agent a. Per block ONCE: each wave gathers its 30
// B-fragments (hi/lo) straight from W1 global -> regs (at fixed (ks,j) the
// 32-lane group reads 128 contiguous bytes -> 2 lines/instr, L2-resident).
// Per tile: coalesced X loads -> hi/lo LDS planes (ASTR 248) -> b128
// fragment reads, zero unpack in MFMA loop. LDS 64000 B -> 2 blocks/CU.
//
// HW-verified in R9's passing first call (absmax 0.0039):
//  - frag map: k = ks*16 + (lane>>5)*8 + j ; B col = half*32 + (lane&31)
//  - C/D: col = lane&31, row = (reg&3) + 8*(reg>>2) + 4*(lane>>5)
//  - msgs: row r uses msgs[r-1], agents j!=a ascending, zeros at t==0
//  - numerics: truncate-hi + RNE-lo, passes (hi*Bh + lo*Bh + hi*Bl)
//  - A-plane uint2 pack / b128 read ; qp split-half epilogue

#define NAGENTS 8
#define MSG_LEN 16
#define OBS_DIM 128
#define HIDDEN  64
#define IN_DIM  240
#define TT      256
#define ROWS    16384
#define KSTEPS  15
#define MTILE   64
#define ASTR    248                  // shorts per A row (240 + 8 pad)
#define TPB     4                    // m-tiles per block
#define GX      (ROWS / (MTILE * TPB))   // 64

typedef __attribute__((ext_vector_type(8)))  short bf16x8;
typedef __attribute__((ext_vector_type(16))) float f32x16;

__device__ __forceinline__ unsigned short f2bf_rne(float x) {
    unsigned u = __float_as_uint(x);
    u += 0x7fffu + ((u >> 16) & 1u);
    return (unsigned short)(u >> 16);
}

__device__ __forceinline__ void load_tile(float4 (&xv)[15],
    const float* __restrict__ obs, const float* __restrict__ msgs,
    int m0, int a, int tid)
{
#pragma unroll
    for (int it = 0; it < 15; ++it) {
        int f4  = tid + it * 256;
        int row = f4 / 60;
        int c   = f4 - row * 60;
        int r   = m0 + row;
        float4 v;
        if (c < 32) {
            v = *reinterpret_cast<const float4*>(
                    obs + ((size_t)r * NAGENTS + a) * OBS_DIM + c * 4);
        } else {
            int p    = (c - 32) >> 2;
            int jsrc = (p < a) ? p : p + 1;
            if ((r & (TT - 1)) == 0) {
                v = make_float4(0.f, 0.f, 0.f, 0.f);
            } else {
                v = *reinterpret_cast<const float4*>(
                        msgs + ((size_t)(r - 1) * NAGENTS + jsrc) * MSG_LEN
                             + ((c - 32) & 3) * 4);
            }
        }
        xv[it] = v;
    }
}

__device__ __forceinline__ void pack_tile(const float4 (&xv)[15],
    unsigned short* __restrict__ sAH, unsigned short* __restrict__ sAL, int tid)
{
#pragma unroll
    for (int it = 0; it < 15; ++it) {
        int f4  = tid + it * 256;
        int row = f4 / 60;
        int c   = f4 - row * 60;
        float fv[4] = { xv[it].x, xv[it].y, xv[it].z, xv[it].w };
        unsigned u[4], h[4]; unsigned short l[4];
#pragma unroll
        for (int i = 0; i < 4; ++i) {
            u[i] = __float_as_uint(fv[i]);
            h[i] = u[i] & 0xffff0000u;
            l[i] = f2bf_rne(fv[i] - __uint_as_float(h[i]));
        }
        uint2 ph, pl;
        ph.x = (u[0] >> 16) | h[1];
        ph.y = (u[2] >> 16) | h[3];
        pl.x = (unsigned)l[0] | ((unsigned)l[1] << 16);
        pl.y = (unsigned)l[2] | ((unsigned)l[3] << 16);
        *reinterpret_cast<uint2*>(&sAH[row * ASTR + c * 4]) = ph;
        *reinterpret_cast<uint2*>(&sAL[row * ASTR + c * 4]) = pl;
    }
}

// One m-tile: pack staged xv -> LDS, optional next-tile load issue, MFMA, epilogue.
#define TILE_BODY(XV, XVN, IT, DO_NEXT)                                         \
    {                                                                           \
        pack_tile(XV, sAH, sAL, tid);                                           \
        __syncthreads();                                                        \
        if (DO_NEXT) load_tile(XVN, obs, msgs, m_base + ((IT) + 1) * MTILE, a, tid); \
        f32x16 acc;                                                             \
        _Pragma("unroll")                                                       \
        for (int i = 0; i < 16; ++i) acc[i] = 0.f;                              \
        _Pragma("unroll")                                                       \
        for (int ks = 0; ks < KSTEPS; ++ks) {                                   \
            int so = arow * ASTR + ks * 16 + kg * 8;                            \
            bf16x8 ahi = *reinterpret_cast<const bf16x8*>(&sAH[so]);            \
            bf16x8 alo = *reinterpret_cast<const bf16x8*>(&sAL[so]);            \
            acc = __builtin_amdgcn_mfma_f32_32x32x16_bf16(ahi, bh[ks], acc, 0, 0, 0); \
            acc = __builtin_amdgcn_mfma_f32_32x32x16_bf16(alo, bh[ks], acc, 0, 0, 0); \
            acc = __builtin_amdgcn_mfma_f32_32x32x16_bf16(ahi, bl[ks], acc, 0, 0, 0); \
        }                                                                       \
        float v[16];                                                            \
        _Pragma("unroll")                                                       \
        for (int i = 0; i < 16; ++i) v[i] = fmaxf(acc[i] + b1v, 0.f) * w2v;     \
        _Pragma("unroll")                                                       \
        for (int off = 16; off >= 1; off >>= 1) {                               \
            _Pragma("unroll")                                                   \
            for (int i = 0; i < 16; ++i) v[i] += __shfl_xor(v[i], off, 64);     \
        }                                                                       \
        if (cl == 0) {                                                          \
            _Pragma("unroll")                                                   \
            for (int i = 0; i < 16; ++i) {                                      \
                int row = (i & 3) + 8 * (i >> 2) + 4 * kg;                      \
                qp[half * 64 + slab * 32 + row] = v[i];                         \
            }                                                                   \
        }                                                                       \
        __syncthreads();                                                        \
        if (tid < MTILE)                                                        \
            out[(size_t)(m_base + (IT) * MTILE + tid) * NAGENTS + a] =          \
                qp[tid] + qp[64 + tid] + b2v;                                   \
    }

__global__ __launch_bounds__(256, 2) void accritic_mfma_v5(
    const float* __restrict__ obs,   // (bs,T,n,128)
    const float* __restrict__ msgs,  // (bs,T,n,16)
    const float* __restrict__ W1,    // (n,240,64)
    const float* __restrict__ b1,    // (n,64)
    const float* __restrict__ W2,    // (n,64,1)
    const float* __restrict__ b2,    // (n,1)
    float* __restrict__ out)         // (bs,T,n,1)
{
    __shared__ __align__(16) unsigned short sAH[MTILE * ASTR];   // 31744 B
    __shared__ __align__(16) unsigned short sAL[MTILE * ASTR];   // 31744 B
    __shared__ float qp[128];                                    // 512 B

    const int a      = blockIdx.y;
    const int g      = blockIdx.x;
    const int tid    = threadIdx.x;
    const int wv     = tid >> 6;
    const int lane   = tid & 63;
    const int slab   = wv & 1;        // 32-row slab
    const int half   = wv >> 1;       // hidden-col half
    const int rl     = lane & 31;
    const int kg     = lane >> 5;
    const int cl     = lane & 31;
    const int arow   = slab * 32 + rl;
    const int m_base = g * (MTILE * TPB);

    // ---- tile-0 X loads issued first: latency hides under the B-gather ----
    float4 xv0[15], xv1[15], xv2[15], xv3[15];
    load_tile(xv0, obs, msgs, m_base, a, tid);

    // ---- B-fragments: direct coalesced gather W1 -> regs (once per block) ----
    // (ks,j) instr: lanes 0..31 read 128 contiguous B; lanes 32..63 the next k-group.
    const float* __restrict__ w1a = W1 + (size_t)a * IN_DIM * HIDDEN;
    bf16x8 bh[KSTEPS], bl[KSTEPS];
#pragma unroll
    for (int ks = 0; ks < KSTEPS; ++ks) {
        const int kbase = ks * 16 + kg * 8;
        const int col   = half * 32 + cl;
        float w[8];
#pragma unroll
        for (int j = 0; j < 8; ++j)
            w[j] = w1a[(size_t)(kbase + j) * HIDDEN + col];
#pragma unroll
        for (int j = 0; j < 8; ++j) {
            unsigned u = __float_as_uint(w[j]);
            bh[ks][j] = (short)(u >> 16);                       // truncate-hi
            bl[ks][j] = (short)f2bf_rne(w[j] - __uint_as_float(u & 0xffff0000u));
        }
    }

    const float b1v = b1[a * HIDDEN + half * 32 + cl];
    const float w2v = W2[a * HIDDEN + half * 32 + cl];
    const float b2v = b2[a];

    TILE_BODY(xv0, xv1, 0, true)
    TILE_BODY(xv1, xv2, 1, true)
    TILE_BODY(xv2, xv3, 2, true)
    TILE_BODY(xv3, xv0, 3, false)
}

extern "C" void kernel_launch(void* const* d_in, const int* in_sizes, int n_in,
                              void* d_out, int out_size, void* d_ws, size_t ws_size,
                              hipStream_t stream) {
    const float* obs  = (const float*)d_in[0];
    const float* msgs = (const float*)d_in[1];
    const float* W1   = (const float*)d_in[2];
    const float* b1   = (const float*)d_in[3];
    const float* W2   = (const float*)d_in[4];
    const float* b2   = (const float*)d_in[5];
    float* out = (float*)d_out;

    accritic_mfma_v5<<<dim3(GX, NAGENTS), dim3(256), 0, stream>>>(
        obs, msgs, W1, b1, W2, b2, out);
}

// Round 11
// 143.630 us; speedup vs baseline: 1.7046x; 1.7046x over previous
//
#include <hip/hip_runtime.h>

// ACCriticNSMsg — v6: v5 with the spill bug fixed (single xv buffer).
// bs=64,T=256,n=8,msg=16,obs=128,hid=64,in_dim=240. out (bs,T,n,1) f32.
//
// R10 post-mortem: v5 (TPB=4 with 4 live xv register tiles) needed ~376 VGPR,
// compiler allocated 128 and spilled -> WRITE_SIZE 97MB of scratch, 176us,
// MfmaUtil 2.6%. v6 keeps the TPB=4 amortized B-gather but reuses ONE xv
// buffer sequentially (live ~210 VGPR: B-frags 120 + xv 60 + acc 16 + temps).
// amdgpu_waves_per_eu(2,2) pins the 256-VGPR budget (LDS 64000B already
// limits to 2 blocks/CU, so nothing is lost).
//
// HW-verified (R9/R10 passing runs, absmax 0.0039):
//  - frag map: k = ks*16 + (lane>>5)*8 + j ; B col = half*32 + (lane&31)
//  - C/D: col = lane&31, row = (reg&3) + 8*(reg>>2) + 4*(lane>>5)
//  - msgs: row r uses msgs[r-1], agents j!=a ascending, zeros at t==0
//  - numerics: truncate-hi + RNE-lo, passes (hi*Bh + lo*Bh + hi*Bl)
//  - ASTR=248 A-plane: b128 reads spread 8 dwords/bank = minimum (no swizzle
//    needed; v5 measured SQ_LDS_BANK_CONFLICT 196k = negligible)

#define NAGENTS 8
#define MSG_LEN 16
#define OBS_DIM 128
#define HIDDEN  64
#define IN_DIM  240
#define TT      256
#define ROWS    16384
#define KSTEPS  15
#define MTILE   64
#define ASTR    248                  // shorts per A row (240 + 8 pad)
#define TPB     4                    // m-tiles per block (sequential)
#define GX      (ROWS / (MTILE * TPB))   // 64

typedef __attribute__((ext_vector_type(8)))  short bf16x8;
typedef __attribute__((ext_vector_type(16))) float f32x16;

__device__ __forceinline__ unsigned short f2bf_rne(float x) {
    unsigned u = __float_as_uint(x);
    u += 0x7fffu + ((u >> 16) & 1u);
    return (unsigned short)(u >> 16);
}

__device__ __forceinline__ void load_tile(float4 (&xv)[15],
    const float* __restrict__ obs, const float* __restrict__ msgs,
    int m0, int a, int tid)
{
#pragma unroll
    for (int it = 0; it < 15; ++it) {
        int f4  = tid + it * 256;
        int row = f4 / 60;
        int c   = f4 - row * 60;
        int r   = m0 + row;
        float4 v;
        if (c < 32) {
            v = *reinterpret_cast<const float4*>(
                    obs + ((size_t)r * NAGENTS + a) * OBS_DIM + c * 4);
        } else {
            int p    = (c - 32) >> 2;
            int jsrc = (p < a) ? p : p + 1;
            if ((r & (TT - 1)) == 0) {
                v = make_float4(0.f, 0.f, 0.f, 0.f);
            } else {
                v = *reinterpret_cast<const float4*>(
                        msgs + ((size_t)(r - 1) * NAGENTS + jsrc) * MSG_LEN
                             + ((c - 32) & 3) * 4);
            }
        }
        xv[it] = v;
    }
}

__device__ __forceinline__ void pack_tile(const float4 (&xv)[15],
    unsigned short* __restrict__ sAH, unsigned short* __restrict__ sAL, int tid)
{
#pragma unroll
    for (int it = 0; it < 15; ++it) {
        int f4  = tid + it * 256;
        int row = f4 / 60;
        int c   = f4 - row * 60;
        float fv[4] = { xv[it].x, xv[it].y, xv[it].z, xv[it].w };
        unsigned u[4], h[4]; unsigned short l[4];
#pragma unroll
        for (int i = 0; i < 4; ++i) {
            u[i] = __float_as_uint(fv[i]);
            h[i] = u[i] & 0xffff0000u;
            l[i] = f2bf_rne(fv[i] - __uint_as_float(h[i]));
        }
        uint2 ph, pl;
        ph.x = (u[0] >> 16) | h[1];
        ph.y = (u[2] >> 16) | h[3];
        pl.x = (unsigned)l[0] | ((unsigned)l[1] << 16);
        pl.y = (unsigned)l[2] | ((unsigned)l[3] << 16);
        *reinterpret_cast<uint2*>(&sAH[row * ASTR + c * 4]) = ph;
        *reinterpret_cast<uint2*>(&sAL[row * ASTR + c * 4]) = pl;
    }
}

__global__ __launch_bounds__(256)
__attribute__((amdgpu_waves_per_eu(2, 2)))
void accritic_mfma_v6(
    const float* __restrict__ obs,   // (bs,T,n,128)
    const float* __restrict__ msgs,  // (bs,T,n,16)
    const float* __restrict__ W1,    // (n,240,64)
    const float* __restrict__ b1,    // (n,64)
    const float* __restrict__ W2,    // (n,64,1)
    const float* __restrict__ b2,    // (n,1)
    float* __restrict__ out)         // (bs,T,n,1)
{
    __shared__ __align__(16) unsigned short sAH[MTILE * ASTR];   // 31744 B
    __shared__ __align__(16) unsigned short sAL[MTILE * ASTR];   // 31744 B
    __shared__ float qp[128];                                    // 512 B

    const int a      = blockIdx.y;
    const int g      = blockIdx.x;
    const int tid    = threadIdx.x;
    const int wv     = tid >> 6;
    const int lane   = tid & 63;
    const int slab   = wv & 1;        // 32-row slab
    const int half   = wv >> 1;       // hidden-col half
    const int rl     = lane & 31;
    const int kg     = lane >> 5;
    const int cl     = lane & 31;
    const int arow   = slab * 32 + rl;
    const int m_base = g * (MTILE * TPB);

    // ---- B-fragments: direct coalesced gather W1 -> regs (once per block) ----
    // (ks,j) instr: 32-lane group reads 128 contiguous bytes; L2-resident.
    const float* __restrict__ w1a = W1 + (size_t)a * IN_DIM * HIDDEN;
    bf16x8 bh[KSTEPS], bl[KSTEPS];
#pragma unroll
    for (int ks = 0; ks < KSTEPS; ++ks) {
        const int kbase = ks * 16 + kg * 8;
        const int col   = half * 32 + cl;
        float w[8];
#pragma unroll
        for (int j = 0; j < 8; ++j)
            w[j] = w1a[(size_t)(kbase + j) * HIDDEN + col];
#pragma unroll
        for (int j = 0; j < 8; ++j) {
            unsigned u = __float_as_uint(w[j]);
            bh[ks][j] = (short)(u >> 16);                       // truncate-hi
            bl[ks][j] = (short)f2bf_rne(w[j] - __uint_as_float(u & 0xffff0000u));
        }
    }

    const float b1v = b1[a * HIDDEN + half * 32 + cl];
    const float w2v = W2[a * HIDDEN + half * 32 + cl];
    const float b2v = b2[a];

    for (int tt = 0; tt < TPB; ++tt) {
        const int m0 = m_base + tt * MTILE;

        // ---- stage X tile: coalesced loads -> hi/lo LDS planes ----
        float4 xv[15];
        load_tile(xv, obs, msgs, m0, a, tid);
        pack_tile(xv, sAH, sAL, tid);
        __syncthreads();

        // ---- MFMA over K: A from LDS (b128, no unpack), B from regs ----
        f32x16 acc;
#pragma unroll
        for (int i = 0; i < 16; ++i) acc[i] = 0.f;
#pragma unroll
        for (int ks = 0; ks < KSTEPS; ++ks) {
            int so = arow * ASTR + ks * 16 + kg * 8;
            bf16x8 ahi = *reinterpret_cast<const bf16x8*>(&sAH[so]);
            bf16x8 alo = *reinterpret_cast<const bf16x8*>(&sAL[so]);
            acc = __builtin_amdgcn_mfma_f32_32x32x16_bf16(ahi, bh[ks], acc, 0, 0, 0);
            acc = __builtin_amdgcn_mfma_f32_32x32x16_bf16(alo, bh[ks], acc, 0, 0, 0);
            acc = __builtin_amdgcn_mfma_f32_32x32x16_bf16(ahi, bl[ks], acc, 0, 0, 0);
        }

        // ---- epilogue: relu + W2 dot + cross-half combine ----
        float v[16];
#pragma unroll
        for (int i = 0; i < 16; ++i) v[i] = fmaxf(acc[i] + b1v, 0.f) * w2v;
#pragma unroll
        for (int off = 16; off >= 1; off >>= 1) {
#pragma unroll
            for (int i = 0; i < 16; ++i) v[i] += __shfl_xor(v[i], off, 64);
        }
        if (cl == 0) {
#pragma unroll
            for (int i = 0; i < 16; ++i) {
                int row = (i & 3) + 8 * (i >> 2) + 4 * kg;   // HW-verified C/D map
                qp[half * 64 + slab * 32 + row] = v[i];
            }
        }
        __syncthreads();
        if (tid < MTILE)
            out[(size_t)(m0 + tid) * NAGENTS + a] = qp[tid] + qp[64 + tid] + b2v;
        // next iteration's pack overwrites sAH/sAL only after this barrier's
        // lgkm drain (qp reads complete), and all MFMA reads preceded qp-write.
    }
}

extern "C" void kernel_launch(void* const* d_in, const int* in_sizes, int n_in,
                              void* d_out, int out_size, void* d_ws, size_t ws_size,
                              hipStream_t stream) {
    const float* obs  = (const float*)d_in[0];
    const float* msgs = (const float*)d_in[1];
    const float* W1   = (const float*)d_in[2];
    const float* b1   = (const float*)d_in[3];
    const float* W2   = (const float*)d_in[4];
    const float* b2   = (const float*)d_in[5];
    float* out = (float*)d_out;

    accritic_mfma_v6<<<dim3(GX, NAGENTS), dim3(256), 0, stream>>>(
        obs, msgs, W1, b1, W2, b2, out);
}